// Round 4
// baseline (812.393 us; speedup 1.0000x reference)
//
#include <hip/hip_runtime.h>
#include <math.h>

#define N_TOK 32768
#define IN_DIM 1024
#define HID 256
#define NE 64

// ---------------------------------------------------------------------------
// Pre-pass: W1[256][1024] -> W1T[1024][256] (1 MB workspace), so the hot
// kernel can stage W rows [k][h] into LDS with pure b128 writes (no
// transpose-scatter, no swizzle).
// ---------------------------------------------------------------------------
__global__ __launch_bounds__(256)
void transpose_w1(const float* __restrict__ w1, float* __restrict__ w1t)
{
    __shared__ float tile[32][33];
    const int k0 = blockIdx.x * 32;
    const int h0 = blockIdx.y * 32;
    const int j  = threadIdx.x & 31;
    const int i0 = threadIdx.x >> 5;
    #pragma unroll
    for (int r = 0; r < 4; ++r) {
        int i = i0 + r * 8;
        tile[i][j] = w1[(size_t)(h0 + i) * IN_DIM + k0 + j];
    }
    __syncthreads();
    #pragma unroll
    for (int r = 0; r < 4; ++r) {
        int i = i0 + r * 8;
        w1t[(size_t)(k0 + i) * HID + h0 + j] = tile[j][i];
    }
}

// ---------------------------------------------------------------------------
// Fused gating network, hybrid dataflow (round-4):
//   phase A: H = relu(X @ W1T + b1).
//     wave = 8 tokens x 256 hidden; lane = 8 tok x 4 hid (acc[8][4]).
//     W: LDS, staged 32-k chunks as [k][256] (b128 writes, b128 reads,
//        1 ds_read_b128/lane/k -> LDS pipe ~94% vs round-2's 160%).
//     X: wave-uniform float2 loads (HW broadcast), double-buffered in regs
//        (32 VGPR only -> no spill; round 3's 128-VGPR blowup avoided).
//   phase B: logits = H @ W2^T + b2. H via LDS (bit-identical k-order);
//     W2 read from L2 (64 KB, resident). top-2 via 16-lane shfl butterfly
//     implementing the same strict (value desc, index asc) order as the
//     serial scan -> bit-identical outputs.
//   Occupancy: LDS 33.3 KB, VGPR ~105 -> 4 blocks/CU; grid 1024 = one full
//   pass over 256 CUs, no tail.
// ---------------------------------------------------------------------------
union SMem {
    float Ws[32][256];   // 32 KB, phase A
    float Hs[32][260];   // 33.3 KB, phase B (pad 260: row stride 1040 B -> 
                         // 8 tokens map to distinct 16B bank slots)
};

__global__ __launch_bounds__(256, 4)
void moe_gate(const float* __restrict__ x,  const float* __restrict__ w1t,
              const float* __restrict__ b1, const float* __restrict__ w2,
              const float* __restrict__ b2, float* __restrict__ out)
{
    __shared__ SMem sm;

    const int tid = threadIdx.x;
    const int w   = tid >> 6;        // wave 0..3 -> tokens w*8 .. w*8+7
    const int l   = tid & 63;        // lane -> hiddens l*4 .. l*4+3
    const int t0  = blockIdx.x * 32;

    const float* xb = x + (size_t)(t0 + w * 8) * IN_DIM;

    float acc[8][4];
    #pragma unroll
    for (int t = 0; t < 8; ++t)
        #pragma unroll
        for (int j = 0; j < 4; ++j) acc[t][j] = 0.f;

    // ---------------- phase A ----------------
    #pragma unroll 1
    for (int c = 0; c < 32; ++c) {
        const int k0 = c * 32;
        __syncthreads();   // chunk c-1 readers done before overwriting Ws
        // stage W1T rows [k0..k0+32) x 256h: 2048 float4, 8/thread, all b128
        #pragma unroll
        for (int r = 0; r < 8; ++r) {
            int slot = tid + 256 * r;
            int k = slot >> 6, c4 = slot & 63;
            float4 v = *(const float4*)(w1t + (size_t)(k0 + k) * HID + c4 * 4);
            *(float4*)&sm.Ws[k][c4 * 4] = v;
        }
        __syncthreads();

        // X double-buffer: xA holds k (kk,kk+1), xB holds (kk+2,kk+3)
        float2 xA[8], xB[8];
        #pragma unroll
        for (int t = 0; t < 8; ++t)
            xA[t] = *(const float2*)(xb + (size_t)t * IN_DIM + k0);
        #pragma unroll
        for (int t = 0; t < 8; ++t)
            xB[t] = *(const float2*)(xb + (size_t)t * IN_DIM + k0 + 2);

        #pragma unroll
        for (int g = 0; g < 8; ++g) {
            const int kk = g * 4;
            float4 w0 = *(const float4*)&sm.Ws[kk + 0][l * 4];
            float4 w1f = *(const float4*)&sm.Ws[kk + 1][l * 4];
            #pragma unroll
            for (int t = 0; t < 8; ++t) {
                acc[t][0] = fmaf(xA[t].x, w0.x, acc[t][0]);
                acc[t][1] = fmaf(xA[t].x, w0.y, acc[t][1]);
                acc[t][2] = fmaf(xA[t].x, w0.z, acc[t][2]);
                acc[t][3] = fmaf(xA[t].x, w0.w, acc[t][3]);
            }
            #pragma unroll
            for (int t = 0; t < 8; ++t) {
                acc[t][0] = fmaf(xA[t].y, w1f.x, acc[t][0]);
                acc[t][1] = fmaf(xA[t].y, w1f.y, acc[t][1]);
                acc[t][2] = fmaf(xA[t].y, w1f.z, acc[t][2]);
                acc[t][3] = fmaf(xA[t].y, w1f.w, acc[t][3]);
            }
            if (g < 7) {  // refill xA for g+1 (k = k0+kk+4,+5)
                #pragma unroll
                for (int t = 0; t < 8; ++t)
                    xA[t] = *(const float2*)(xb + (size_t)t * IN_DIM + k0 + kk + 4);
            }
            float4 w2f = *(const float4*)&sm.Ws[kk + 2][l * 4];
            float4 w3f = *(const float4*)&sm.Ws[kk + 3][l * 4];
            #pragma unroll
            for (int t = 0; t < 8; ++t) {
                acc[t][0] = fmaf(xB[t].x, w2f.x, acc[t][0]);
                acc[t][1] = fmaf(xB[t].x, w2f.y, acc[t][1]);
                acc[t][2] = fmaf(xB[t].x, w2f.z, acc[t][2]);
                acc[t][3] = fmaf(xB[t].x, w2f.w, acc[t][3]);
            }
            #pragma unroll
            for (int t = 0; t < 8; ++t) {
                acc[t][0] = fmaf(xB[t].y, w3f.x, acc[t][0]);
                acc[t][1] = fmaf(xB[t].y, w3f.y, acc[t][1]);
                acc[t][2] = fmaf(xB[t].y, w3f.z, acc[t][2]);
                acc[t][3] = fmaf(xB[t].y, w3f.w, acc[t][3]);
            }
            if (g < 7) {  // refill xB for g+1 (k = k0+kk+6,+7)
                #pragma unroll
                for (int t = 0; t < 8; ++t)
                    xB[t] = *(const float2*)(xb + (size_t)t * IN_DIM + k0 + kk + 6);
            }
        }
    }

    // bias + relu
    {
        float4 bb = *(const float4*)(b1 + l * 4);
        #pragma unroll
        for (int t = 0; t < 8; ++t) {
            acc[t][0] = fmaxf(acc[t][0] + bb.x, 0.f);
            acc[t][1] = fmaxf(acc[t][1] + bb.y, 0.f);
            acc[t][2] = fmaxf(acc[t][2] + bb.z, 0.f);
            acc[t][3] = fmaxf(acc[t][3] + bb.w, 0.f);
        }
    }

    __syncthreads();   // all waves done reading Ws before Hs overwrites it
    // dump H: [tok][hid], b128 writes, lane-stride 16 B (conflict-free)
    #pragma unroll
    for (int i = 0; i < 8; ++i) {
        float4 hv = make_float4(acc[i][0], acc[i][1], acc[i][2], acc[i][3]);
        *(float4*)&sm.Hs[w * 8 + i][l * 4] = hv;
    }
    __syncthreads();

    // ---------------- phase B: logits + top-2 + softmax ----------------
    const int tp = tid >> 4;   // 0..15 -> tokens tp*2, tp*2+1
    const int e4 = tid & 15;   // 0..15 -> experts e4*4 .. e4*4+3

    const float* h0p = &sm.Hs[tp * 2][0];
    const float* h1p = &sm.Hs[tp * 2 + 1][0];
    const float* w2p = w2 + (size_t)(e4 * 4) * HID;

    float acc2[2][4];
    #pragma unroll
    for (int i = 0; i < 2; ++i)
        #pragma unroll
        for (int j = 0; j < 4; ++j) acc2[i][j] = 0.f;

    #pragma unroll 4
    for (int k4 = 0; k4 < 64; ++k4) {
        const int k = k4 * 4;
        float4 hv0 = *(const float4*)(h0p + k);
        float4 hv1 = *(const float4*)(h1p + k);
        float4 e0 = *(const float4*)(w2p + 0 * HID + k);
        float4 e1 = *(const float4*)(w2p + 1 * HID + k);
        float4 e2 = *(const float4*)(w2p + 2 * HID + k);
        float4 e3 = *(const float4*)(w2p + 3 * HID + k);
        // k ascending: .x, .y, .z, .w in order (bit-exact vs serial k-loop)
        acc2[0][0] = fmaf(hv0.x, e0.x, acc2[0][0]);
        acc2[0][1] = fmaf(hv0.x, e1.x, acc2[0][1]);
        acc2[0][2] = fmaf(hv0.x, e2.x, acc2[0][2]);
        acc2[0][3] = fmaf(hv0.x, e3.x, acc2[0][3]);
        acc2[1][0] = fmaf(hv1.x, e0.x, acc2[1][0]);
        acc2[1][1] = fmaf(hv1.x, e1.x, acc2[1][1]);
        acc2[1][2] = fmaf(hv1.x, e2.x, acc2[1][2]);
        acc2[1][3] = fmaf(hv1.x, e3.x, acc2[1][3]);
        acc2[0][0] = fmaf(hv0.y, e0.y, acc2[0][0]);
        acc2[0][1] = fmaf(hv0.y, e1.y, acc2[0][1]);
        acc2[0][2] = fmaf(hv0.y, e2.y, acc2[0][2]);
        acc2[0][3] = fmaf(hv0.y, e3.y, acc2[0][3]);
        acc2[1][0] = fmaf(hv1.y, e0.y, acc2[1][0]);
        acc2[1][1] = fmaf(hv1.y, e1.y, acc2[1][1]);
        acc2[1][2] = fmaf(hv1.y, e2.y, acc2[1][2]);
        acc2[1][3] = fmaf(hv1.y, e3.y, acc2[1][3]);
        acc2[0][0] = fmaf(hv0.z, e0.z, acc2[0][0]);
        acc2[0][1] = fmaf(hv0.z, e1.z, acc2[0][1]);
        acc2[0][2] = fmaf(hv0.z, e2.z, acc2[0][2]);
        acc2[0][3] = fmaf(hv0.z, e3.z, acc2[0][3]);
        acc2[1][0] = fmaf(hv1.z, e0.z, acc2[1][0]);
        acc2[1][1] = fmaf(hv1.z, e1.z, acc2[1][1]);
        acc2[1][2] = fmaf(hv1.z, e2.z, acc2[1][2]);
        acc2[1][3] = fmaf(hv1.z, e3.z, acc2[1][3]);
        acc2[0][0] = fmaf(hv0.w, e0.w, acc2[0][0]);
        acc2[0][1] = fmaf(hv0.w, e1.w, acc2[0][1]);
        acc2[0][2] = fmaf(hv0.w, e2.w, acc2[0][2]);
        acc2[0][3] = fmaf(hv0.w, e3.w, acc2[0][3]);
        acc2[1][0] = fmaf(hv1.w, e0.w, acc2[1][0]);
        acc2[1][1] = fmaf(hv1.w, e1.w, acc2[1][1]);
        acc2[1][2] = fmaf(hv1.w, e2.w, acc2[1][2]);
        acc2[1][3] = fmaf(hv1.w, e3.w, acc2[1][3]);
    }

    // + b2, then per-token top-2 across the 16 lanes of the e4 dimension.
    float4 b2v = *(const float4*)(b2 + e4 * 4);
    #pragma unroll
    for (int i = 0; i < 2; ++i) {
        float v[4] = {acc2[i][0] + b2v.x, acc2[i][1] + b2v.y,
                      acc2[i][2] + b2v.z, acc2[i][3] + b2v.w};
        // local top-2 of 4 (ascending index, strict > -> lower idx on ties)
        float m1 = -INFINITY, m2 = -INFINITY;
        int i1 = 0, i2 = 0;
        #pragma unroll
        for (int j = 0; j < 4; ++j) {
            int e = e4 * 4 + j;
            if (v[j] > m1)      { m2 = m1; i2 = i1; m1 = v[j]; i1 = e; }
            else if (v[j] > m2) { m2 = v[j]; i2 = e; }
        }
        // butterfly merge over the 16-lane group (same strict total order)
        #pragma unroll
        for (int off = 1; off < 16; off <<= 1) {
            float om1 = __shfl_xor(m1, off);
            int   oi1 = __shfl_xor(i1, off);
            float om2 = __shfl_xor(m2, off);
            int   oi2 = __shfl_xor(i2, off);
            bool bwin = (om1 > m1) || (om1 == m1 && oi1 < i1);
            float c1v = bwin ? om1 : m1;  int c1i = bwin ? oi1 : i1;
            float lv  = bwin ? m1  : om1; int li  = bwin ? i1  : oi1;
            float w2v = bwin ? om2 : m2;  int w2i = bwin ? oi2 : i2;
            bool s = (lv > w2v) || (lv == w2v && li < w2i);
            m1 = c1v; i1 = c1i;
            m2 = s ? lv : w2v; i2 = s ? li : w2i;
        }
        if (e4 == 0) {
            float ex  = expf(m2 - m1);          // <= 1
            float inv = 1.f / (1.f + ex);
            int gt = t0 + tp * 2 + i;
            out[(size_t)gt * 2 + 0] = (float)i1;
            out[(size_t)gt * 2 + 1] = (float)i2;
            out[(size_t)2 * N_TOK + (size_t)gt * 2 + 0] = inv;
            out[(size_t)2 * N_TOK + (size_t)gt * 2 + 1] = ex * inv;
        }
    }
}

extern "C" void kernel_launch(void* const* d_in, const int* in_sizes, int n_in,
                              void* d_out, int out_size, void* d_ws, size_t ws_size,
                              hipStream_t stream) {
    const float* x  = (const float*)d_in[0];  // [32768,1024]
    const float* w1 = (const float*)d_in[1];  // [256,1024]
    const float* b1 = (const float*)d_in[2];  // [256]
    const float* w2 = (const float*)d_in[3];  // [64,256]
    const float* b2 = (const float*)d_in[4];  // [64]
    float* out = (float*)d_out;               // 131072 floats: idx then gates
    float* w1t = (float*)d_ws;                // W1T [1024][256], 1 MB

    transpose_w1<<<dim3(32, 8), 256, 0, stream>>>(w1, w1t);
    moe_gate<<<N_TOK / 32, 256, 0, stream>>>(x, w1t, b1, w2, b2, out);
}

// Round 5
// 624.898 us; speedup vs baseline: 1.3000x; 1.3000x over previous
//
#include <hip/hip_runtime.h>
#include <math.h>

#define N_TOK 32768
#define IN_DIM 1024
#define HID 256
#define NE 64

// ---------------------------------------------------------------------------
// Pre-pass: W1[256][1024] -> W1T[1024][256] (1 MB workspace), so the hot
// kernel can stage W rows [k][h] into LDS with pure b128 writes (no
// transpose-scatter, no swizzle).
// ---------------------------------------------------------------------------
__global__ __launch_bounds__(256)
void transpose_w1(const float* __restrict__ w1, float* __restrict__ w1t)
{
    __shared__ float tile[32][33];
    const int k0 = blockIdx.x * 32;
    const int h0 = blockIdx.y * 32;
    const int j  = threadIdx.x & 31;
    const int i0 = threadIdx.x >> 5;
    #pragma unroll
    for (int r = 0; r < 4; ++r) {
        int i = i0 + r * 8;
        tile[i][j] = w1[(size_t)(h0 + i) * IN_DIM + k0 + j];
    }
    __syncthreads();
    #pragma unroll
    for (int r = 0; r < 4; ++r) {
        int i = i0 + r * 8;
        w1t[(size_t)(k0 + i) * HID + h0 + j] = tile[j][i];
    }
}

// ---------------------------------------------------------------------------
// Fused gating network, hybrid dataflow (round-5 = round-4 with the register
// allocator un-strangled):
//   ROUND-4 LESSON: __launch_bounds__(256,4) made the allocator round down to
//   the 64-VGPR occupancy bucket; without aligned 4-reg tuples it scalarized
//   every LDS float4 access into 4x ds_read_b32 at 16B lane stride = 8 lanes
//   per bank -> SQ_LDS_BANK_CONFLICT 1.27e8, VALUBusy 24%, 698 us.
//   (256,2) is the setting rounds 2/3 compiled sanely under (92/128 VGPR,
//   b128 intact). LDS = 33.3 KB still caps residency at 4 blocks/CU, so we
//   keep 16 waves/CU as long as VGPR <= 128 (~96 expected).
//
//   phase A: H = relu(X @ W1T + b1).
//     wave = 8 tokens x 256 hidden; lane = 8 tok x 4 hid (acc[8][4]).
//     W: LDS, staged 32-k chunks as [k][256] (b128 writes, b128 reads,
//        1 ds_read_b128/lane/k; per-CU LDS demand ~240 cyc vs 256 VALU-issue
//        cyc per k -> VALU is the limiter, unlike round-2's 1.5x oversub).
//     X: wave-uniform float2 loads (HW broadcast), double-buffered in regs
//        (32 VGPR).
//   phase B: logits = H @ W2^T + b2. H via LDS; W2 from L2 (64 KB resident).
//     top-2 via 16-lane shfl butterfly with strict (value desc, index asc)
//     order == serial scan -> bit-identical outputs (verified round 4).
// ---------------------------------------------------------------------------
union SMem {
    float Ws[32][256];   // 32 KB, phase A
    float Hs[32][260];   // 33.3 KB, phase B (pad 260: row stride 1040 B)
};

__global__ __launch_bounds__(256, 2)
void moe_gate(const float* __restrict__ x,  const float* __restrict__ w1t,
              const float* __restrict__ b1, const float* __restrict__ w2,
              const float* __restrict__ b2, float* __restrict__ out)
{
    __shared__ SMem sm;

    const int tid = threadIdx.x;
    const int w   = tid >> 6;        // wave 0..3 -> tokens w*8 .. w*8+7
    const int l   = tid & 63;        // lane -> hiddens l*4 .. l*4+3
    const int t0  = blockIdx.x * 32;

    const float* xb = x + (size_t)(t0 + w * 8) * IN_DIM;

    float acc[8][4];
    #pragma unroll
    for (int t = 0; t < 8; ++t)
        #pragma unroll
        for (int j = 0; j < 4; ++j) acc[t][j] = 0.f;

    // ---------------- phase A ----------------
    #pragma unroll 1
    for (int c = 0; c < 32; ++c) {
        const int k0 = c * 32;
        __syncthreads();   // chunk c-1 readers done before overwriting Ws
        // stage W1T rows [k0..k0+32) x 256h: 2048 float4, 8/thread, all b128
        #pragma unroll
        for (int r = 0; r < 8; ++r) {
            int slot = tid + 256 * r;
            int k = slot >> 6, c4 = slot & 63;
            float4 v = *(const float4*)(w1t + (size_t)(k0 + k) * HID + c4 * 4);
            *(float4*)&sm.Ws[k][c4 * 4] = v;
        }
        __syncthreads();

        // X double-buffer: xA holds k (kk,kk+1), xB holds (kk+2,kk+3)
        float2 xA[8], xB[8];
        #pragma unroll
        for (int t = 0; t < 8; ++t)
            xA[t] = *(const float2*)(xb + (size_t)t * IN_DIM + k0);
        #pragma unroll
        for (int t = 0; t < 8; ++t)
            xB[t] = *(const float2*)(xb + (size_t)t * IN_DIM + k0 + 2);

        #pragma unroll
        for (int g = 0; g < 8; ++g) {
            const int kk = g * 4;
            float4 w0 = *(const float4*)&sm.Ws[kk + 0][l * 4];
            float4 w1f = *(const float4*)&sm.Ws[kk + 1][l * 4];
            #pragma unroll
            for (int t = 0; t < 8; ++t) {
                acc[t][0] = fmaf(xA[t].x, w0.x, acc[t][0]);
                acc[t][1] = fmaf(xA[t].x, w0.y, acc[t][1]);
                acc[t][2] = fmaf(xA[t].x, w0.z, acc[t][2]);
                acc[t][3] = fmaf(xA[t].x, w0.w, acc[t][3]);
            }
            #pragma unroll
            for (int t = 0; t < 8; ++t) {
                acc[t][0] = fmaf(xA[t].y, w1f.x, acc[t][0]);
                acc[t][1] = fmaf(xA[t].y, w1f.y, acc[t][1]);
                acc[t][2] = fmaf(xA[t].y, w1f.z, acc[t][2]);
                acc[t][3] = fmaf(xA[t].y, w1f.w, acc[t][3]);
            }
            if (g < 7) {  // refill xA for g+1 (k = k0+kk+4,+5)
                #pragma unroll
                for (int t = 0; t < 8; ++t)
                    xA[t] = *(const float2*)(xb + (size_t)t * IN_DIM + k0 + kk + 4);
            }
            float4 w2f = *(const float4*)&sm.Ws[kk + 2][l * 4];
            float4 w3f = *(const float4*)&sm.Ws[kk + 3][l * 4];
            #pragma unroll
            for (int t = 0; t < 8; ++t) {
                acc[t][0] = fmaf(xB[t].x, w2f.x, acc[t][0]);
                acc[t][1] = fmaf(xB[t].x, w2f.y, acc[t][1]);
                acc[t][2] = fmaf(xB[t].x, w2f.z, acc[t][2]);
                acc[t][3] = fmaf(xB[t].x, w2f.w, acc[t][3]);
            }
            #pragma unroll
            for (int t = 0; t < 8; ++t) {
                acc[t][0] = fmaf(xB[t].y, w3f.x, acc[t][0]);
                acc[t][1] = fmaf(xB[t].y, w3f.y, acc[t][1]);
                acc[t][2] = fmaf(xB[t].y, w3f.z, acc[t][2]);
                acc[t][3] = fmaf(xB[t].y, w3f.w, acc[t][3]);
            }
            if (g < 7) {  // refill xB for g+1 (k = k0+kk+6,+7)
                #pragma unroll
                for (int t = 0; t < 8; ++t)
                    xB[t] = *(const float2*)(xb + (size_t)t * IN_DIM + k0 + kk + 6);
            }
        }
    }

    // bias + relu
    {
        float4 bb = *(const float4*)(b1 + l * 4);
        #pragma unroll
        for (int t = 0; t < 8; ++t) {
            acc[t][0] = fmaxf(acc[t][0] + bb.x, 0.f);
            acc[t][1] = fmaxf(acc[t][1] + bb.y, 0.f);
            acc[t][2] = fmaxf(acc[t][2] + bb.z, 0.f);
            acc[t][3] = fmaxf(acc[t][3] + bb.w, 0.f);
        }
    }

    __syncthreads();   // all waves done reading Ws before Hs overwrites it
    // dump H: [tok][hid], b128 writes, lane-stride 16 B (conflict-free)
    #pragma unroll
    for (int i = 0; i < 8; ++i) {
        float4 hv = make_float4(acc[i][0], acc[i][1], acc[i][2], acc[i][3]);
        *(float4*)&sm.Hs[w * 8 + i][l * 4] = hv;
    }
    __syncthreads();

    // ---------------- phase B: logits + top-2 + softmax ----------------
    const int tp = tid >> 4;   // 0..15 -> tokens tp*2, tp*2+1
    const int e4 = tid & 15;   // 0..15 -> experts e4*4 .. e4*4+3

    const float* h0p = &sm.Hs[tp * 2][0];
    const float* h1p = &sm.Hs[tp * 2 + 1][0];
    const float* w2p = w2 + (size_t)(e4 * 4) * HID;

    float acc2[2][4];
    #pragma unroll
    for (int i = 0; i < 2; ++i)
        #pragma unroll
        for (int j = 0; j < 4; ++j) acc2[i][j] = 0.f;

    #pragma unroll 4
    for (int k4 = 0; k4 < 64; ++k4) {
        const int k = k4 * 4;
        float4 hv0 = *(const float4*)(h0p + k);
        float4 hv1 = *(const float4*)(h1p + k);
        float4 e0 = *(const float4*)(w2p + 0 * HID + k);
        float4 e1 = *(const float4*)(w2p + 1 * HID + k);
        float4 e2 = *(const float4*)(w2p + 2 * HID + k);
        float4 e3 = *(const float4*)(w2p + 3 * HID + k);
        // k ascending: .x, .y, .z, .w in order (bit-exact vs serial k-loop)
        acc2[0][0] = fmaf(hv0.x, e0.x, acc2[0][0]);
        acc2[0][1] = fmaf(hv0.x, e1.x, acc2[0][1]);
        acc2[0][2] = fmaf(hv0.x, e2.x, acc2[0][2]);
        acc2[0][3] = fmaf(hv0.x, e3.x, acc2[0][3]);
        acc2[1][0] = fmaf(hv1.x, e0.x, acc2[1][0]);
        acc2[1][1] = fmaf(hv1.x, e1.x, acc2[1][1]);
        acc2[1][2] = fmaf(hv1.x, e2.x, acc2[1][2]);
        acc2[1][3] = fmaf(hv1.x, e3.x, acc2[1][3]);
        acc2[0][0] = fmaf(hv0.y, e0.y, acc2[0][0]);
        acc2[0][1] = fmaf(hv0.y, e1.y, acc2[0][1]);
        acc2[0][2] = fmaf(hv0.y, e2.y, acc2[0][2]);
        acc2[0][3] = fmaf(hv0.y, e3.y, acc2[0][3]);
        acc2[1][0] = fmaf(hv1.y, e0.y, acc2[1][0]);
        acc2[1][1] = fmaf(hv1.y, e1.y, acc2[1][1]);
        acc2[1][2] = fmaf(hv1.y, e2.y, acc2[1][2]);
        acc2[1][3] = fmaf(hv1.y, e3.y, acc2[1][3]);
        acc2[0][0] = fmaf(hv0.z, e0.z, acc2[0][0]);
        acc2[0][1] = fmaf(hv0.z, e1.z, acc2[0][1]);
        acc2[0][2] = fmaf(hv0.z, e2.z, acc2[0][2]);
        acc2[0][3] = fmaf(hv0.z, e3.z, acc2[0][3]);
        acc2[1][0] = fmaf(hv1.z, e0.z, acc2[1][0]);
        acc2[1][1] = fmaf(hv1.z, e1.z, acc2[1][1]);
        acc2[1][2] = fmaf(hv1.z, e2.z, acc2[1][2]);
        acc2[1][3] = fmaf(hv1.z, e3.z, acc2[1][3]);
        acc2[0][0] = fmaf(hv0.w, e0.w, acc2[0][0]);
        acc2[0][1] = fmaf(hv0.w, e1.w, acc2[0][1]);
        acc2[0][2] = fmaf(hv0.w, e2.w, acc2[0][2]);
        acc2[0][3] = fmaf(hv0.w, e3.w, acc2[0][3]);
        acc2[1][0] = fmaf(hv1.w, e0.w, acc2[1][0]);
        acc2[1][1] = fmaf(hv1.w, e1.w, acc2[1][1]);
        acc2[1][2] = fmaf(hv1.w, e2.w, acc2[1][2]);
        acc2[1][3] = fmaf(hv1.w, e3.w, acc2[1][3]);
    }

    // + b2, then per-token top-2 across the 16 lanes of the e4 dimension.
    float4 b2v = *(const float4*)(b2 + e4 * 4);
    #pragma unroll
    for (int i = 0; i < 2; ++i) {
        float v[4] = {acc2[i][0] + b2v.x, acc2[i][1] + b2v.y,
                      acc2[i][2] + b2v.z, acc2[i][3] + b2v.w};
        // local top-2 of 4 (ascending index, strict > -> lower idx on ties)
        float m1 = -INFINITY, m2 = -INFINITY;
        int i1 = 0, i2 = 0;
        #pragma unroll
        for (int j = 0; j < 4; ++j) {
            int e = e4 * 4 + j;
            if (v[j] > m1)      { m2 = m1; i2 = i1; m1 = v[j]; i1 = e; }
            else if (v[j] > m2) { m2 = v[j]; i2 = e; }
        }
        // butterfly merge over the 16-lane group (same strict total order)
        #pragma unroll
        for (int off = 1; off < 16; off <<= 1) {
            float om1 = __shfl_xor(m1, off);
            int   oi1 = __shfl_xor(i1, off);
            float om2 = __shfl_xor(m2, off);
            int   oi2 = __shfl_xor(i2, off);
            bool bwin = (om1 > m1) || (om1 == m1 && oi1 < i1);
            float c1v = bwin ? om1 : m1;  int c1i = bwin ? oi1 : i1;
            float lv  = bwin ? m1  : om1; int li  = bwin ? i1  : oi1;
            float w2v = bwin ? om2 : m2;  int w2i = bwin ? oi2 : i2;
            bool s = (lv > w2v) || (lv == w2v && li < w2i);
            m1 = c1v; i1 = c1i;
            m2 = s ? lv : w2v; i2 = s ? li : w2i;
        }
        if (e4 == 0) {
            float ex  = expf(m2 - m1);          // <= 1
            float inv = 1.f / (1.f + ex);
            int gt = t0 + tp * 2 + i;
            out[(size_t)gt * 2 + 0] = (float)i1;
            out[(size_t)gt * 2 + 1] = (float)i2;
            out[(size_t)2 * N_TOK + (size_t)gt * 2 + 0] = inv;
            out[(size_t)2 * N_TOK + (size_t)gt * 2 + 1] = ex * inv;
        }
    }
}

extern "C" void kernel_launch(void* const* d_in, const int* in_sizes, int n_in,
                              void* d_out, int out_size, void* d_ws, size_t ws_size,
                              hipStream_t stream) {
    const float* x  = (const float*)d_in[0];  // [32768,1024]
    const float* w1 = (const float*)d_in[1];  // [256,1024]
    const float* b1 = (const float*)d_in[2];  // [256]
    const float* w2 = (const float*)d_in[3];  // [64,256]
    const float* b2 = (const float*)d_in[4];  // [64]
    float* out = (float*)d_out;               // 131072 floats: idx then gates
    float* w1t = (float*)d_ws;                // W1T [1024][256], 1 MB

    transpose_w1<<<dim3(32, 8), 256, 0, stream>>>(w1, w1t);
    moe_gate<<<N_TOK / 32, 256, 0, stream>>>(x, w1t, b1, w2, b2, out);
}

// Round 6
// 412.433 us; speedup vs baseline: 1.9698x; 1.5152x over previous
//
#include <hip/hip_runtime.h>
#include <math.h>

#define N_TOK 32768
#define IN_DIM 1024
#define HID 256
#define NE 64

// ---------------------------------------------------------------------------
// Fused gating network — round-6: round-2's PROVEN access patterns (the only
// config measured conflict-free at speed: 258us, SQ_LDS_BANK_CONFLICT ~1e6),
// rescaled from 64-tok/256-thr to 32-tok/128-thr blocks.
//
// WHY: R2's VALUBusy capped at 56% with grid=512 = exactly 2 barrier domains
// per CU; stage-drain stalls (vmcnt(0)+barrier) in both domains overlap and
// idle the CU. Same per-wave LDS/VALU demand at 1024 blocks -> 4 independent
// domains/CU (LDS 36KB x 4 = 144KB), all blocks co-resident, no tail.
//
// LDS law learned in R4/R5 (conflicts 1.266e8, invariant under VGPR alloc):
// wave64 b128 reads with 64 distinct 16B slots (lane l at l*16, 1024B span)
// cost ~30 extra cyc/op. R2's pattern — 32 distinct slots, 2-way lane
// broadcast (hg=tid&31 reads groups {hg^m, (hg^m)+32}) — measures ~free.
// Everything below keeps that pattern exactly.
// ---------------------------------------------------------------------------
union SMem {
    struct { float Xs[32][32]; float Ws[32][256]; } a;  // 4K + 32K = 36K
    float Hs[32][260];                                  // 33.25K (pad 260)
};

__global__ __launch_bounds__(128, 2)
void moe_gate(const float* __restrict__ x,  const float* __restrict__ w1,
              const float* __restrict__ b1, const float* __restrict__ w2,
              const float* __restrict__ b2, float* __restrict__ out)
{
    __shared__ SMem sm;

    const int tid = threadIdx.x;
    const int tg  = tid >> 5;       // 0..3  -> tokens tg*8 .. tg*8+7
    const int hg  = tid & 31;       // 0..31 -> hiddens {hg*4..+3, 128+hg*4..+3}
    const int t0  = blockIdx.x * 32;

    float acc[8][8];
    #pragma unroll
    for (int i = 0; i < 8; ++i)
        #pragma unroll
        for (int j = 0; j < 8; ++j) acc[i][j] = 0.f;

    // ---------------- phase A: H = relu(X @ W1^T + b1) ----------------
    #pragma unroll 1
    for (int c = 0; c < 32; ++c) {
        const int k0 = c * 32;
        // stage X tile: 32 tok x 32 k = 256 float4, 2 per thread.
        // swizzled transpose (R2 formula): 2-way write aliasing = free.
        #pragma unroll
        for (int r = 0; r < 2; ++r) {
            int slot = tid + 128 * r;
            int t = slot >> 3, kq = (slot & 7) * 4;
            float4 v = *(const float4*)(x + (size_t)(t0 + t) * IN_DIM + k0 + kq);
            int col = (((t >> 2) ^ (kq >> 2)) << 2) | (t & 3);
            sm.a.Xs[kq + 0][col] = v.x;
            sm.a.Xs[kq + 1][col] = v.y;
            sm.a.Xs[kq + 2][col] = v.z;
            sm.a.Xs[kq + 3][col] = v.w;
        }
        // stage W1 tile: 256 h x 32 k = 2048 float4, 16 per thread
        #pragma unroll
        for (int r = 0; r < 16; ++r) {
            int slot = tid + 128 * r;
            int hh = slot >> 3, kq = (slot & 7) * 4;
            float4 v = *(const float4*)(w1 + (size_t)hh * IN_DIM + k0 + kq);
            int col = (((hh >> 2) ^ (kq >> 2)) << 2) | (hh & 3);
            sm.a.Ws[kq + 0][col] = v.x;
            sm.a.Ws[kq + 1][col] = v.y;
            sm.a.Ws[kq + 2][col] = v.z;
            sm.a.Ws[kq + 3][col] = v.w;
        }
        __syncthreads();

        // inner product: swizzle key (k>>2)==m constant per m-group ->
        // bases hoisted, ds_read offsets are immediates. W reads: 32 distinct
        // 16B slots + 2-way lane broadcast (the conflict-free pattern).
        #pragma unroll
        for (int m = 0; m < 8; ++m) {
            const float* xb0 = &sm.a.Xs[0][(((tg * 2)     ^ m) << 2)];
            const float* xb1 = &sm.a.Xs[0][(((tg * 2 + 1) ^ m) << 2)];
            const float* wb0 = &sm.a.Ws[0][(( hg ^ m)         << 2)];
            const float* wb1 = &sm.a.Ws[0][((((hg ^ m) + 32)) << 2)];
            #pragma unroll
            for (int kk = 0; kk < 4; ++kk) {
                int k = m * 4 + kk;
                float4 xv0 = *(const float4*)(xb0 + k * 32);
                float4 xv1 = *(const float4*)(xb1 + k * 32);
                float4 wv0 = *(const float4*)(wb0 + k * 256);
                float4 wv1 = *(const float4*)(wb1 + k * 256);
                float xv[8] = {xv0.x, xv0.y, xv0.z, xv0.w, xv1.x, xv1.y, xv1.z, xv1.w};
                float wv[8] = {wv0.x, wv0.y, wv0.z, wv0.w, wv1.x, wv1.y, wv1.z, wv1.w};
                #pragma unroll
                for (int i = 0; i < 8; ++i)
                    #pragma unroll
                    for (int j = 0; j < 8; ++j)
                        acc[i][j] = fmaf(xv[i], wv[j], acc[i][j]);
            }
        }
        __syncthreads();
    }

    // bias + relu (acc[i][j]: j 0..3 -> h=hg*4+j, j 4..7 -> h=128+hg*4+(j-4))
    {
        float4 bb0 = *(const float4*)(b1 + hg * 4);
        float4 bb1 = *(const float4*)(b1 + 128 + hg * 4);
        float bias1[8] = {bb0.x, bb0.y, bb0.z, bb0.w, bb1.x, bb1.y, bb1.z, bb1.w};
        #pragma unroll
        for (int i = 0; i < 8; ++i)
            #pragma unroll
            for (int j = 0; j < 8; ++j)
                acc[i][j] = fmaxf(acc[i][j] + bias1[j], 0.f);
    }

    // dump H -> LDS [tok][hid] (end-of-loop barrier already drained readers;
    // b128 writes, rows 1040B, 2-way bank aliasing = free)
    #pragma unroll
    for (int i = 0; i < 8; ++i) {
        *(float4*)&sm.Hs[tg * 8 + i][hg * 4] =
            make_float4(acc[i][0], acc[i][1], acc[i][2], acc[i][3]);
        *(float4*)&sm.Hs[tg * 8 + i][128 + hg * 4] =
            make_float4(acc[i][4], acc[i][5], acc[i][6], acc[i][7]);
    }
    __syncthreads();

    // ---------------- phase B: logits + top-2 + softmax (R5-proven) --------
    const int tp = tid >> 4;   // 0..7  -> tokens tp*4 .. tp*4+3
    const int e4 = tid & 15;   // 0..15 -> experts e4*4 .. e4*4+3

    const float* hp[4] = { &sm.Hs[tp * 4 + 0][0], &sm.Hs[tp * 4 + 1][0],
                           &sm.Hs[tp * 4 + 2][0], &sm.Hs[tp * 4 + 3][0] };
    const float* w2p = w2 + (size_t)(e4 * 4) * HID;

    float acc2[4][4];
    #pragma unroll
    for (int i = 0; i < 4; ++i)
        #pragma unroll
        for (int j = 0; j < 4; ++j) acc2[i][j] = 0.f;

    #pragma unroll 2
    for (int k4 = 0; k4 < 64; ++k4) {
        const int k = k4 * 4;
        float hvv[4][4], evv[4][4];
        #pragma unroll
        for (int i = 0; i < 4; ++i)
            *(float4*)&hvv[i][0] = *(const float4*)(hp[i] + k);   // 16-way bcast
        #pragma unroll
        for (int j = 0; j < 4; ++j)
            *(float4*)&evv[j][0] = *(const float4*)(w2p + (size_t)j * HID + k);
        // k ascending within the quad (d = 0..3): bit-exact vs serial k-loop
        #pragma unroll
        for (int d = 0; d < 4; ++d)
            #pragma unroll
            for (int i = 0; i < 4; ++i)
                #pragma unroll
                for (int j = 0; j < 4; ++j)
                    acc2[i][j] = fmaf(hvv[i][d], evv[j][d], acc2[i][j]);
    }

    // + b2, then per-token top-2 across the 16 e4-lanes (strict total order
    // (value desc, index asc) == jax.lax.top_k; verified rounds 4/5).
    float4 b2v = *(const float4*)(b2 + e4 * 4);
    #pragma unroll
    for (int i = 0; i < 4; ++i) {
        float v[4] = {acc2[i][0] + b2v.x, acc2[i][1] + b2v.y,
                      acc2[i][2] + b2v.z, acc2[i][3] + b2v.w};
        float m1 = -INFINITY, m2 = -INFINITY;
        int i1 = 0, i2 = 0;
        #pragma unroll
        for (int j = 0; j < 4; ++j) {
            int e = e4 * 4 + j;
            if (v[j] > m1)      { m2 = m1; i2 = i1; m1 = v[j]; i1 = e; }
            else if (v[j] > m2) { m2 = v[j]; i2 = e; }
        }
        #pragma unroll
        for (int off = 1; off < 16; off <<= 1) {
            float om1 = __shfl_xor(m1, off);
            int   oi1 = __shfl_xor(i1, off);
            float om2 = __shfl_xor(m2, off);
            int   oi2 = __shfl_xor(i2, off);
            bool bwin = (om1 > m1) || (om1 == m1 && oi1 < i1);
            float c1v = bwin ? om1 : m1;  int c1i = bwin ? oi1 : i1;
            float lv  = bwin ? m1  : om1; int li  = bwin ? i1  : oi1;
            float w2v = bwin ? om2 : m2;  int w2i = bwin ? oi2 : i2;
            bool s = (lv > w2v) || (lv == w2v && li < w2i);
            m1 = c1v; i1 = c1i;
            m2 = s ? lv : w2v; i2 = s ? li : w2i;
        }
        if (e4 == 0) {
            float ex  = expf(m2 - m1);          // <= 1, no overflow
            float inv = 1.f / (1.f + ex);
            int gt = t0 + tp * 4 + i;
            out[(size_t)gt * 2 + 0] = (float)i1;
            out[(size_t)gt * 2 + 1] = (float)i2;
            out[(size_t)2 * N_TOK + (size_t)gt * 2 + 0] = inv;
            out[(size_t)2 * N_TOK + (size_t)gt * 2 + 1] = ex * inv;
        }
    }
}

extern "C" void kernel_launch(void* const* d_in, const int* in_sizes, int n_in,
                              void* d_out, int out_size, void* d_ws, size_t ws_size,
                              hipStream_t stream) {
    const float* x  = (const float*)d_in[0];  // [32768,1024]
    const float* w1 = (const float*)d_in[1];  // [256,1024]
    const float* b1 = (const float*)d_in[2];  // [256]
    const float* w2 = (const float*)d_in[3];  // [64,256]
    const float* b2 = (const float*)d_in[4];  // [64]
    float* out = (float*)d_out;               // 131072 floats: idx then gates

    moe_gate<<<N_TOK / 32, 128, 0, stream>>>(x, w1, b1, w2, b2, out);
}